// Round 1
// baseline (237.152 us; speedup 1.0000x reference)
//
#include <hip/hip_runtime.h>

#define D_FEAT 64

// COO SpMM baseline: one 64-lane wave per edge, lane = feature dim.
// out[row[e]*64 + lane] += val[e] * x[col[e]*64 + lane]  via device-scope atomicAdd.
__global__ void spmm_atomic_kernel(const float* __restrict__ x,
                                   const int* __restrict__ row,
                                   const int* __restrict__ col,
                                   const float* __restrict__ val,
                                   float* __restrict__ out,
                                   int n_edges) {
    int gid = blockIdx.x * blockDim.x + threadIdx.x;
    int e = gid >> 6;          // wave id = edge id
    int lane = gid & 63;       // feature dim
    if (e >= n_edges) return;
    int r = row[e];
    int c = col[e];
    float v = val[e];
    float xv = x[(size_t)c * D_FEAT + lane];   // coalesced 256B gather per wave
    atomicAdd(&out[(size_t)r * D_FEAT + lane], v * xv);
}

extern "C" void kernel_launch(void* const* d_in, const int* in_sizes, int n_in,
                              void* d_out, int out_size, void* d_ws, size_t ws_size,
                              hipStream_t stream) {
    const float* x   = (const float*)d_in[0];
    const int*   row = (const int*)d_in[1];
    const int*   col = (const int*)d_in[2];
    const float* val = (const float*)d_in[3];
    // d_in[4] is idx (no-op constant selecting the single adjacency)
    float* out = (float*)d_out;
    int n_edges = in_sizes[1];

    // d_out is poisoned (0xAA) and never re-zeroed between graph replays:
    // zero it ourselves every call (async, capture-safe).
    hipMemsetAsync(d_out, 0, (size_t)out_size * sizeof(float), stream);

    const int threads = 256;                 // 4 waves = 4 edges per block
    const int edges_per_block = threads / 64;
    int blocks = (n_edges + edges_per_block - 1) / edges_per_block;
    spmm_atomic_kernel<<<blocks, threads, 0, stream>>>(x, row, col, val, out, n_edges);
}

// Round 2
// 211.419 us; speedup vs baseline: 1.1217x; 1.1217x over previous
//
#include <hip/hip_runtime.h>

#define N_NODES 65536
#define D_FEAT  64

// ---------- workspace layout ----------
// cursor/counts : int[N_NODES]     @ 0        (256 KB)  histogram, then scatter cursor
// offsets       : int[N_NODES+1]   @ 0x40000  (256 KB + 4)
// pairs         : int2[n_edges]    @ 0x100000 (8 MB)    CSR-ordered {col, val}

// Phase 1: histogram of row ids
__global__ void hist_kernel(const int* __restrict__ row, int* __restrict__ counts, int n) {
    int i = blockIdx.x * blockDim.x + threadIdx.x;
    if (i < n) atomicAdd(&counts[row[i]], 1);
}

// Phase 2: exclusive scan of 65536 counts, single block of 1024 threads (64 elems each).
// Writes offsets[0..N] and re-initializes cursor[] = exclusive offsets (in place over counts).
__global__ void scan_kernel(int* __restrict__ counts_cursor, int* __restrict__ offsets) {
    __shared__ int sums[1024];
    int t = threadIdx.x;
    int base = t * 64;
    int local[64];
    int s = 0;
    const int4* c4 = (const int4*)(counts_cursor + base);
    #pragma unroll
    for (int k = 0; k < 16; ++k) {
        int4 v = c4[k];
        local[4*k+0] = v.x; local[4*k+1] = v.y; local[4*k+2] = v.z; local[4*k+3] = v.w;
        s += v.x + v.y + v.z + v.w;
    }
    sums[t] = s;
    __syncthreads();
    // Hillis-Steele inclusive scan over 1024 partial sums
    for (int d = 1; d < 1024; d <<= 1) {
        int add = (t >= d) ? sums[t - d] : 0;
        __syncthreads();
        sums[t] += add;
        __syncthreads();
    }
    int running = sums[t] - s;   // exclusive prefix for this thread's chunk
    #pragma unroll
    for (int k = 0; k < 64; ++k) {
        offsets[base + k] = running;
        counts_cursor[base + k] = running;   // scatter cursor (safe: own chunk already in regs)
        running += local[k];
    }
    if (t == 1023) offsets[N_NODES] = running;
}

// Phase 3: scatter (col,val) into CSR order
__global__ void scatter_kernel(const int* __restrict__ row, const int* __restrict__ col,
                               const float* __restrict__ val, int* __restrict__ cursor,
                               int2* __restrict__ pairs, int n) {
    int i = blockIdx.x * blockDim.x + threadIdx.x;
    if (i < n) {
        int r = row[i];
        int pos = atomicAdd(&cursor[r], 1);
        pairs[pos] = make_int2(col[i], __float_as_int(val[i]));
    }
}

// Phase 4: CSR SpMM — one 64-lane wave per row, lane = feature dim, register accumulate.
__global__ void spmm_csr_kernel(const float* __restrict__ x, const int* __restrict__ offsets,
                                const int2* __restrict__ pairs, float* __restrict__ out) {
    int gid = blockIdx.x * blockDim.x + threadIdx.x;
    int r = gid >> 6;
    int lane = gid & 63;
    if (r >= N_NODES) return;
    int beg = offsets[r], end = offsets[r + 1];
    float acc = 0.f;
    int e = beg;
    for (; e + 1 < end; e += 2) {              // unroll 2 for load ILP
        int2 p0 = pairs[e];
        int2 p1 = pairs[e + 1];
        float x0 = x[(size_t)p0.x * D_FEAT + lane];
        float x1 = x[(size_t)p1.x * D_FEAT + lane];
        acc += __int_as_float(p0.y) * x0;
        acc += __int_as_float(p1.y) * x1;
    }
    if (e < end) {
        int2 p = pairs[e];
        acc += __int_as_float(p.y) * x[(size_t)p.x * D_FEAT + lane];
    }
    out[(size_t)r * D_FEAT + lane] = acc;
}

// Fallback (ws too small): round-1 atomic kernel
__global__ void spmm_atomic_kernel(const float* __restrict__ x, const int* __restrict__ row,
                                   const int* __restrict__ col, const float* __restrict__ val,
                                   float* __restrict__ out, int n_edges) {
    int gid = blockIdx.x * blockDim.x + threadIdx.x;
    int e = gid >> 6;
    int lane = gid & 63;
    if (e >= n_edges) return;
    atomicAdd(&out[(size_t)row[e] * D_FEAT + lane], val[e] * x[(size_t)col[e] * D_FEAT + lane]);
}

extern "C" void kernel_launch(void* const* d_in, const int* in_sizes, int n_in,
                              void* d_out, int out_size, void* d_ws, size_t ws_size,
                              hipStream_t stream) {
    const float* x   = (const float*)d_in[0];
    const int*   row = (const int*)d_in[1];
    const int*   col = (const int*)d_in[2];
    const float* val = (const float*)d_in[3];
    float* out = (float*)d_out;
    int n_edges = in_sizes[1];

    size_t need = 0x100000 + (size_t)n_edges * sizeof(int2);
    if (ws_size < need) {
        // fallback: atomic COO (known-correct, 237 us)
        hipMemsetAsync(d_out, 0, (size_t)out_size * sizeof(float), stream);
        int blocks = (n_edges * 64 + 255) / 256;
        spmm_atomic_kernel<<<blocks, 256, 0, stream>>>(x, row, col, val, out, n_edges);
        return;
    }

    char* ws = (char*)d_ws;
    int*  cursor  = (int*)(ws);             // doubles as counts
    int*  offsets = (int*)(ws + 0x40000);
    int2* pairs   = (int2*)(ws + 0x100000);

    hipMemsetAsync(cursor, 0, N_NODES * sizeof(int), stream);

    int eb = (n_edges + 255) / 256;
    hist_kernel<<<eb, 256, 0, stream>>>(row, cursor, n_edges);
    scan_kernel<<<1, 1024, 0, stream>>>(cursor, offsets);
    scatter_kernel<<<eb, 256, 0, stream>>>(row, col, val, cursor, pairs, n_edges);

    int rb = (N_NODES * 64 + 255) / 256;    // 4 rows (waves) per 256-thread block
    spmm_csr_kernel<<<rb, 256, 0, stream>>>(x, offsets, pairs, out);
}

// Round 3
// 184.161 us; speedup vs baseline: 1.2877x; 1.1480x over previous
//
#include <hip/hip_runtime.h>

#define N_NODES 65536
#define D_FEAT  64

// ---------- workspace layout ----------
// cursor  : int[N_NODES]      @ 0        (256 KB)  counts -> scatter cursor
// offsets : int[N_NODES+1]    @ 0x40000  (256 KB + 4)
// bsums   : int[256]          @ 0x80100
// pairs   : u64[n_edges]      @ 0x100000 (8 MB)    CSR-ordered {col | val<<32}

// Phase 1: histogram of row ids (4 edges/thread via int4)
__global__ void hist_kernel(const int* __restrict__ row, int* __restrict__ counts, int n) {
    int i4 = blockIdx.x * blockDim.x + threadIdx.x;
    int base = i4 * 4;
    if (base + 3 < n) {
        int4 r = reinterpret_cast<const int4*>(row)[i4];
        atomicAdd(&counts[r.x], 1);
        atomicAdd(&counts[r.y], 1);
        atomicAdd(&counts[r.z], 1);
        atomicAdd(&counts[r.w], 1);
    } else {
        for (int i = base; i < n; ++i) atomicAdd(&counts[row[i]], 1);
    }
}

// Phase 2a: per-block exclusive scan of 256 counts; emit block sums.
__global__ void scan_local_kernel(const int* __restrict__ counts, int* __restrict__ offsets,
                                  int* __restrict__ bsums) {
    __shared__ int sh[256];
    int t = threadIdx.x;
    int i = blockIdx.x * 256 + t;
    int c = counts[i];
    sh[t] = c;
    __syncthreads();
    for (int d = 1; d < 256; d <<= 1) {
        int add = (t >= d) ? sh[t - d] : 0;
        __syncthreads();
        sh[t] += add;
        __syncthreads();
    }
    offsets[i] = sh[t] - c;                  // exclusive within block
    if (t == 255) bsums[blockIdx.x] = sh[255];
}

// Phase 2b: exclusive scan of the 256 block sums (single tiny block).
__global__ void scan_bsums_kernel(int* __restrict__ bsums) {
    __shared__ int sh[256];
    int t = threadIdx.x;
    int c = bsums[t];
    sh[t] = c;
    __syncthreads();
    for (int d = 1; d < 256; d <<= 1) {
        int add = (t >= d) ? sh[t - d] : 0;
        __syncthreads();
        sh[t] += add;
        __syncthreads();
    }
    bsums[t] = sh[t] - c;                    // exclusive
}

// Phase 2c: add block prefix; init cursor; finalize offsets[N]=E.
__global__ void scan_add_kernel(int* __restrict__ offsets, const int* __restrict__ bsums,
                                int* __restrict__ cursor, int n_edges) {
    int i = blockIdx.x * 256 + threadIdx.x;
    int off = offsets[i] + bsums[blockIdx.x];
    offsets[i] = off;
    cursor[i] = off;
    if (i == 0) offsets[N_NODES] = n_edges;
}

// Phase 3: scatter (col,val) packed u64 into CSR order, non-temporal stores.
__global__ void scatter_kernel(const int* __restrict__ row, const int* __restrict__ col,
                               const float* __restrict__ val, int* __restrict__ cursor,
                               unsigned long long* __restrict__ pairs, int n) {
    int i4 = blockIdx.x * blockDim.x + threadIdx.x;
    int base = i4 * 4;
    if (base + 3 < n) {
        int4 r = reinterpret_cast<const int4*>(row)[i4];
        int4 c = reinterpret_cast<const int4*>(col)[i4];
        float4 v = reinterpret_cast<const float4*>(val)[i4];
        int p0 = atomicAdd(&cursor[r.x], 1);
        int p1 = atomicAdd(&cursor[r.y], 1);
        int p2 = atomicAdd(&cursor[r.z], 1);
        int p3 = atomicAdd(&cursor[r.w], 1);
        __builtin_nontemporal_store((unsigned long long)(unsigned)c.x | ((unsigned long long)__float_as_uint(v.x) << 32), &pairs[p0]);
        __builtin_nontemporal_store((unsigned long long)(unsigned)c.y | ((unsigned long long)__float_as_uint(v.y) << 32), &pairs[p1]);
        __builtin_nontemporal_store((unsigned long long)(unsigned)c.z | ((unsigned long long)__float_as_uint(v.z) << 32), &pairs[p2]);
        __builtin_nontemporal_store((unsigned long long)(unsigned)c.w | ((unsigned long long)__float_as_uint(v.w) << 32), &pairs[p3]);
    } else {
        for (int i = base; i < n; ++i) {
            int pos = atomicAdd(&cursor[row[i]], 1);
            unsigned long long pk = (unsigned long long)(unsigned)col[i] |
                                    ((unsigned long long)__float_as_uint(val[i]) << 32);
            __builtin_nontemporal_store(pk, &pairs[pos]);
        }
    }
}

// Phase 4: CSR SpMM — one 64-lane wave per row, lane = feature dim, unroll 4.
__global__ void spmm_csr_kernel(const float* __restrict__ x, const int* __restrict__ offsets,
                                const unsigned long long* __restrict__ pairs,
                                float* __restrict__ out) {
    int gid = blockIdx.x * blockDim.x + threadIdx.x;
    int r = gid >> 6;
    int lane = gid & 63;
    if (r >= N_NODES) return;
    int beg = offsets[r], end = offsets[r + 1];
    float acc = 0.f;
    int e = beg;
    for (; e + 4 <= end; e += 4) {
        unsigned long long p0 = pairs[e + 0];
        unsigned long long p1 = pairs[e + 1];
        unsigned long long p2 = pairs[e + 2];
        unsigned long long p3 = pairs[e + 3];
        float x0 = x[(size_t)(unsigned)(p0 & 0xFFFFFFFFu) * D_FEAT + lane];
        float x1 = x[(size_t)(unsigned)(p1 & 0xFFFFFFFFu) * D_FEAT + lane];
        float x2 = x[(size_t)(unsigned)(p2 & 0xFFFFFFFFu) * D_FEAT + lane];
        float x3 = x[(size_t)(unsigned)(p3 & 0xFFFFFFFFu) * D_FEAT + lane];
        acc += __uint_as_float((unsigned)(p0 >> 32)) * x0;
        acc += __uint_as_float((unsigned)(p1 >> 32)) * x1;
        acc += __uint_as_float((unsigned)(p2 >> 32)) * x2;
        acc += __uint_as_float((unsigned)(p3 >> 32)) * x3;
    }
    for (; e < end; ++e) {
        unsigned long long p = pairs[e];
        acc += __uint_as_float((unsigned)(p >> 32)) *
               x[(size_t)(unsigned)(p & 0xFFFFFFFFu) * D_FEAT + lane];
    }
    out[(size_t)r * D_FEAT + lane] = acc;
}

// Fallback (ws too small): atomic COO
__global__ void spmm_atomic_kernel(const float* __restrict__ x, const int* __restrict__ row,
                                   const int* __restrict__ col, const float* __restrict__ val,
                                   float* __restrict__ out, int n_edges) {
    int gid = blockIdx.x * blockDim.x + threadIdx.x;
    int e = gid >> 6;
    int lane = gid & 63;
    if (e >= n_edges) return;
    atomicAdd(&out[(size_t)row[e] * D_FEAT + lane], val[e] * x[(size_t)col[e] * D_FEAT + lane]);
}

extern "C" void kernel_launch(void* const* d_in, const int* in_sizes, int n_in,
                              void* d_out, int out_size, void* d_ws, size_t ws_size,
                              hipStream_t stream) {
    const float* x   = (const float*)d_in[0];
    const int*   row = (const int*)d_in[1];
    const int*   col = (const int*)d_in[2];
    const float* val = (const float*)d_in[3];
    float* out = (float*)d_out;
    int n_edges = in_sizes[1];

    size_t need = 0x100000 + (size_t)n_edges * sizeof(unsigned long long);
    if (ws_size < need) {
        hipMemsetAsync(d_out, 0, (size_t)out_size * sizeof(float), stream);
        int blocks = (n_edges * 64 + 255) / 256;
        spmm_atomic_kernel<<<blocks, 256, 0, stream>>>(x, row, col, val, out, n_edges);
        return;
    }

    char* ws = (char*)d_ws;
    int*  cursor  = (int*)(ws);
    int*  offsets = (int*)(ws + 0x40000);
    int*  bsums   = (int*)(ws + 0x80100);
    unsigned long long* pairs = (unsigned long long*)(ws + 0x100000);

    hipMemsetAsync(cursor, 0, N_NODES * sizeof(int), stream);

    int e4b = ((n_edges + 3) / 4 + 255) / 256;
    hist_kernel<<<e4b, 256, 0, stream>>>(row, cursor, n_edges);
    scan_local_kernel<<<N_NODES / 256, 256, 0, stream>>>(cursor, offsets, bsums);
    scan_bsums_kernel<<<1, 256, 0, stream>>>(bsums);
    scan_add_kernel<<<N_NODES / 256, 256, 0, stream>>>(offsets, bsums, cursor, n_edges);
    scatter_kernel<<<e4b, 256, 0, stream>>>(row, col, val, cursor, pairs, n_edges);

    int rb = (N_NODES * 64 + 255) / 256;    // 4 rows (waves) per 256-thread block
    spmm_csr_kernel<<<rb, 256, 0, stream>>>(x, offsets, pairs, out);
}